// Round 4
// baseline (751.623 us; speedup 1.0000x reference)
//
#include <hip/hip_runtime.h>
#include <hip/hip_bf16.h>

typedef unsigned int u32;

#define MROWS 4096
#define LOG2E 1.4426950408889634f

// ---------------- A (int32 0/1) -> bitmask (4096 x 128 u32) ----------------
__global__ __launch_bounds__(256) void bits_kernel(const int* __restrict__ A,
                                                   u32* __restrict__ Abits) {
    const int lane = threadIdx.x & 63;
    const int wid  = (blockIdx.x * blockDim.x + threadIdx.x) >> 6;
    const int nw   = (gridDim.x * blockDim.x) >> 6;
    const int nseg = MROWS * (MROWS / 64);
    for (int seg = wid; seg < nseg; seg += nw) {
        const int i  = seg >> 6;
        const int j0 = (seg & 63) * 64;
        int aval = A[(size_t)i * MROWS + j0 + lane];
        unsigned long long bal = __ballot(aval != 0);
        if (lane == 0)      Abits[(size_t)i * 128 + (j0 >> 5)]     = (u32)bal;
        else if (lane == 1) Abits[(size_t)i * 128 + (j0 >> 5) + 1] = (u32)(bal >> 32);
    }
}

// ---------------- GEMM (fp32 VALU): C[m][n] = sum_k A[m][k]*B[n][k] + bias[n] ----------------
// A: 4096 x K rowmajor fp32. B: Nreal x K rowmajor fp32 (rows >= Nreal guarded).
__global__ __launch_bounds__(256) void gemm_nt(const float* __restrict__ A,
                                               const float* __restrict__ B,
                                               const float* __restrict__ bias,
                                               int K, int Nreal, int ldC,
                                               float* __restrict__ Cf) {
    __shared__ float Al[64][20];
    __shared__ float Bl[64][20];
    const int tid = threadIdx.x;
    const int m0 = blockIdx.x * 64, n0 = blockIdx.y * 64;
    const int ty = tid >> 4, tx = tid & 15;      // 16x16 threads, 4x4 outputs each
    const int lr = tid >> 2, lc = (tid & 3) * 4; // staging: 64 rows x 16 k

    float acc[4][4] = {};
    for (int k0 = 0; k0 < K; k0 += 16) {
        float4 av = *(const float4*)&A[(size_t)(m0 + lr) * K + k0 + lc];
        float4 bv = make_float4(0.f, 0.f, 0.f, 0.f);
        if (n0 + lr < Nreal)
            bv = *(const float4*)&B[(size_t)(n0 + lr) * K + k0 + lc];
        __syncthreads();
        *(float4*)&Al[lr][lc] = av;
        *(float4*)&Bl[lr][lc] = bv;
        __syncthreads();
#pragma unroll
        for (int kk = 0; kk < 16; kk += 4) {
            float4 a4[4], b4[4];
#pragma unroll
            for (int r = 0; r < 4; ++r) a4[r] = *(const float4*)&Al[ty * 4 + r][kk];
#pragma unroll
            for (int c = 0; c < 4; ++c) b4[c] = *(const float4*)&Bl[tx * 4 + c][kk];
#pragma unroll
            for (int r = 0; r < 4; ++r)
#pragma unroll
                for (int c = 0; c < 4; ++c)
                    acc[r][c] += a4[r].x * b4[c].x + a4[r].y * b4[c].y +
                                 a4[r].z * b4[c].z + a4[r].w * b4[c].w;
        }
    }
#pragma unroll
    for (int r = 0; r < 4; ++r) {
        const int m = m0 + ty * 4 + r;
#pragma unroll
        for (int c = 0; c < 4; ++c) {
            const int n = n0 + tx * 4 + c;
            if (n < Nreal)
                Cf[(size_t)m * ldC + n] = acc[r][c] + bias[n];
        }
    }
}

// ---------------- scores from Wh (4096x256 fp32): srcT/dstT [h][i] ----------------
__global__ __launch_bounds__(256) void srcdst_row(const float* __restrict__ Whf,
                                                  const float* __restrict__ a,
                                                  float* __restrict__ srcT,
                                                  float* __restrict__ dstT) {
    const int wv = threadIdx.x >> 6, lane = threadIdx.x & 63;
    const int i = blockIdx.x * 4 + wv;
#pragma unroll
    for (int h = 0; h < 4; ++h) {
        const float v = Whf[(size_t)i * 256 + h * 64 + lane];
        float s = v * a[h * 128 + lane];
        float d = v * a[h * 128 + 64 + lane];
        s += __shfl_xor(s, 1);  d += __shfl_xor(d, 1);
        s += __shfl_xor(s, 2);  d += __shfl_xor(d, 2);
        s += __shfl_xor(s, 4);  d += __shfl_xor(d, 4);
        s += __shfl_xor(s, 8);  d += __shfl_xor(d, 8);
        s += __shfl_xor(s, 16); d += __shfl_xor(d, 16);
        s += __shfl_xor(s, 32); d += __shfl_xor(d, 32);
        if (lane == 0) {
            srcT[h * MROWS + i] = s;
            dstT[h * MROWS + i] = d;
        }
    }
}

// ---------------- per-head max of dstT ----------------
__global__ __launch_bounds__(256) void dmax_kernel(const float* __restrict__ dstT,
                                                   float* __restrict__ dm) {
    __shared__ float red[256];
    const int h = blockIdx.x;
    float m = -3.4e38f;
    for (int i = threadIdx.x; i < MROWS; i += 256) m = fmaxf(m, dstT[h * MROWS + i]);
    red[threadIdx.x] = m;
    __syncthreads();
    for (int s = 128; s > 0; s >>= 1) {
        if (threadIdx.x < s) red[threadIdx.x] = fmaxf(red[threadIdx.x], red[threadIdx.x + s]);
        __syncthreads();
    }
    if (threadIdx.x == 0) dm[h] = red[0];
}

// ---------------- attention (fp32 VALU) ----------------
// grid 512 blocks x 256 thr (4 waves = 4 heads), 8 i-rows per block.
// phase1: thread (h, jj=lane) computes w(i, j0+jj) for 8 i's -> LDS.
// phase2: thread (h, c=lane) accumulates acc[i] += w * Wh[j][h*64+c].
#define IB 8
__global__ __launch_bounds__(256) void attn_valu(const float* __restrict__ Whf,
                                                 const float* __restrict__ srcT,
                                                 const float* __restrict__ dstT,
                                                 const u32* __restrict__ Abits,
                                                 const float* __restrict__ dm,
                                                 float* __restrict__ outF) {
    __shared__ float wL[4][64][12];
    const int tid = threadIdx.x;
    const int h = tid >> 6, lane = tid & 63;
    const int i0 = blockIdx.x * IB;
    const float dmh = dm[h];

    float s_[IB], C_[IB], rs_[IB], acc_[IB];
#pragma unroll
    for (int ii = 0; ii < IB; ++ii) {
        const float s = srcT[h * MROWS + i0 + ii];
        s_[ii] = s;
        const float sd = s + dmh;
        C_[ii] = fmaxf(sd, 0.01f * sd);   // leaky_relu of per-row upper bound -> w' <= 1
        rs_[ii] = 0.f;
        acc_[ii] = 0.f;
    }

    for (int j0 = 0; j0 < MROWS; j0 += 64) {
        const float dj = dstT[h * MROWS + j0 + lane];
        const int widx = (j0 >> 5) + (lane >> 5);
        const u32 bsel = 1u << (lane & 31);
#pragma unroll
        for (int ii = 0; ii < IB; ++ii) {
            const u32 word = Abits[(size_t)(i0 + ii) * 128 + widx];
            float t = s_[ii] + dj;
            t = fmaxf(t, 0.01f * t);                       // leaky_relu, slope 0.01
            float w = exp2f((t - C_[ii]) * LOG2E);         // exp(t - C), <= 1
            w = (word & bsel) ? w : 0.f;
            rs_[ii] += w;
            wL[h][lane][ii] = w;
        }
        __syncthreads();
#pragma unroll 4
        for (int jj = 0; jj < 64; ++jj) {
            const float whv = Whf[(size_t)(j0 + jj) * 256 + h * 64 + lane];
            const float4 w0 = *(const float4*)&wL[h][jj][0];
            const float4 w1 = *(const float4*)&wL[h][jj][4];
            acc_[0] += w0.x * whv; acc_[1] += w0.y * whv;
            acc_[2] += w0.z * whv; acc_[3] += w0.w * whv;
            acc_[4] += w1.x * whv; acc_[5] += w1.y * whv;
            acc_[6] += w1.z * whv; acc_[7] += w1.w * whv;
        }
        __syncthreads();
    }

    // full row-sums: butterfly over the 64 jj-lanes
#pragma unroll
    for (int ii = 0; ii < IB; ++ii) {
        float r = rs_[ii];
        r += __shfl_xor(r, 1);  r += __shfl_xor(r, 2);  r += __shfl_xor(r, 4);
        r += __shfl_xor(r, 8);  r += __shfl_xor(r, 16); r += __shfl_xor(r, 32);
        rs_[ii] = r;
    }
#pragma unroll
    for (int ii = 0; ii < IB; ++ii)
        outF[(size_t)(i0 + ii) * 256 + h * 64 + lane] = acc_[ii] / rs_[ii];
}

extern "C" void kernel_launch(void* const* d_in, const int* in_sizes, int n_in,
                              void* d_out, int out_size, void* d_ws, size_t ws_size,
                              hipStream_t stream) {
    const float* hIn = (const float*)d_in[0];
    const int*   A   = (const int*)d_in[1];
    const float* W1w = (const float*)d_in[2];
    const float* W1b = (const float*)d_in[3];
    const float* a1  = (const float*)d_in[4];
    const float* W3w = (const float*)d_in[5];
    const float* W3b = (const float*)d_in[6];
    const float* W2w = (const float*)d_in[7];
    const float* W2b = (const float*)d_in[8];
    const float* a2  = (const float*)d_in[9];
    const float* FLw = (const float*)d_in[10];
    const float* FLb = (const float*)d_in[11];
    float* outX = (float*)d_out;                     // x: (4096 x 256) fp32
    float* outL = outX + (size_t)MROWS * 256;        // logits: (4096 x 40) fp32

    char* p = (char*)d_ws;
    auto alloc = [&](size_t bytes) { char* q = p; p += (bytes + 255) & ~(size_t)255; return q; };
    u32*   Abits = (u32*)alloc((size_t)MROWS * 128 * 4);
    float* Wh1f  = (float*)alloc((size_t)MROWS * 256 * 4);
    float* x1f   = (float*)alloc((size_t)MROWS * 256 * 4);
    float* x3f   = (float*)alloc((size_t)MROWS * 64 * 4);
    float* Wh2f  = (float*)alloc((size_t)MROWS * 256 * 4);
    float* srcT1 = (float*)alloc((size_t)4 * MROWS * 4);
    float* dstT1 = (float*)alloc((size_t)4 * MROWS * 4);
    float* srcT2 = (float*)alloc((size_t)4 * MROWS * 4);
    float* dstT2 = (float*)alloc((size_t)4 * MROWS * 4);
    float* dm1   = (float*)alloc(4 * 4);
    float* dm2   = (float*)alloc(4 * 4);

    dim3 blk(256);
    bits_kernel<<<dim3(2048), blk, 0, stream>>>(A, Abits);

    // ---- layer 1: Wh1 = h @ W1^T + b1 ----
    gemm_nt<<<dim3(64, 4), blk, 0, stream>>>(hIn, W1w, W1b, 512, 256, 256, Wh1f);
    srcdst_row<<<dim3(1024), blk, 0, stream>>>(Wh1f, a1, srcT1, dstT1);
    dmax_kernel<<<dim3(4), blk, 0, stream>>>(dstT1, dm1);
    attn_valu<<<dim3(MROWS / IB), blk, 0, stream>>>(Wh1f, srcT1, dstT1, Abits, dm1, x1f);

    // ---- x3 = x1 @ W3^T + b3 ; Wh2 = x3 @ W2^T + b2 ----
    gemm_nt<<<dim3(64, 1), blk, 0, stream>>>(x1f, W3w, W3b, 256, 64, 64, x3f);
    gemm_nt<<<dim3(64, 4), blk, 0, stream>>>(x3f, W2w, W2b, 64, 256, 256, Wh2f);

    // ---- layer 2: write x straight into d_out (fp32) ----
    srcdst_row<<<dim3(1024), blk, 0, stream>>>(Wh2f, a2, srcT2, dstT2);
    dmax_kernel<<<dim3(4), blk, 0, stream>>>(dstT2, dm2);
    attn_valu<<<dim3(MROWS / IB), blk, 0, stream>>>(Wh2f, srcT2, dstT2, Abits, dm2, outX);

    // ---- classifier head: out1 = x @ FL^T + FL_b (fp32) ----
    gemm_nt<<<dim3(64, 1), blk, 0, stream>>>(outX, FLw, FLb, 256, 40, 40, outL);
}

// Round 5
// 321.492 us; speedup vs baseline: 2.3379x; 2.3379x over previous
//
#include <hip/hip_runtime.h>
#include <hip/hip_bf16.h>

typedef _Float16 f16_t;
typedef unsigned short u16;
typedef unsigned int u32;
typedef float f32x4 __attribute__((ext_vector_type(4)));
typedef f16_t f16x8 __attribute__((ext_vector_type(8)));
typedef u16 u16x8 __attribute__((ext_vector_type(8)));
typedef u16 u16x4 __attribute__((ext_vector_type(4)));

#define MROWS 4096
#define NHEADS 4
#define COUT 64
#define OHF 256   // NHEADS*COUT
#define NCLS 40
#define LOG2E 1.4426950408889634f

static __device__ __forceinline__ u16 f16b(float x) {
    return __builtin_bit_cast(u16, (f16_t)x);
}

// ---------------- A (int32 0/1) -> bitmask (4096 x 128 u32) ----------------
__global__ __launch_bounds__(256) void bits_kernel(const int* __restrict__ A,
                                                   u32* __restrict__ Abits) {
    const int lane = threadIdx.x & 63;
    const int wid  = (blockIdx.x * blockDim.x + threadIdx.x) >> 6;
    const int nw   = (gridDim.x * blockDim.x) >> 6;
    const int nseg = MROWS * (MROWS / 64);
    for (int seg = wid; seg < nseg; seg += nw) {
        const int i  = seg >> 6;
        const int j0 = (seg & 63) * 64;
        int aval = A[(size_t)i * MROWS + j0 + lane];
        unsigned long long bal = __ballot(aval != 0);
        if (lane == 0)      Abits[(size_t)i * 128 + (j0 >> 5)]     = (u32)bal;
        else if (lane == 1) Abits[(size_t)i * 128 + (j0 >> 5) + 1] = (u32)(bal >> 32);
    }
}

// ---------------- Cwf = W2_w @ W3_w (256x256 fp32), cbf = W2_w@W3_b + W2_b ----------------
__global__ __launch_bounds__(256) void cw_kernel(const float* __restrict__ W2,
                                                 const float* __restrict__ W3,
                                                 const float* __restrict__ W3b,
                                                 const float* __restrict__ W2b,
                                                 float* __restrict__ Cwf,
                                                 float* __restrict__ cbf) {
    const int p = blockIdx.x, q = threadIdx.x;
    float acc = 0.f;
    for (int t = 0; t < 64; ++t)
        acc += W2[p * 64 + t] * W3[t * 256 + q];
    Cwf[p * 256 + q] = acc;
    if (q == 0) {
        float b = 0.f;
        for (int t = 0; t < 64; ++t) b += W2[p * 64 + t] * W3b[t];
        cbf[p] = b + W2b[p];
    }
}

// ---------------- va[h][s][k] = sum_c W[(h*64+c)*K + k] * a[h*128 + s*64 + c] ----------------
__global__ __launch_bounds__(256) void va_kernel(const float* __restrict__ W,
                                                 const float* __restrict__ bias,
                                                 const float* __restrict__ a,
                                                 int K,
                                                 float* __restrict__ va,
                                                 float* __restrict__ vc) {
    const int h = blockIdx.y >> 1, s = blockIdx.y & 1;
    const int k = blockIdx.x * 256 + threadIdx.x;
    if (k < K) {
        float acc = 0.f;
        for (int c = 0; c < COUT; ++c)
            acc += W[(size_t)(h * COUT + c) * K + k] * a[h * 128 + s * COUT + c];
        va[(size_t)(h * 2 + s) * K + k] = acc;
    }
    if (blockIdx.x == 0 && threadIdx.x == 0) {
        float b = 0.f;
        for (int c = 0; c < COUT; ++c)
            b += bias[h * COUT + c] * a[h * 128 + s * COUT + c];
        vc[h * 2 + s] = b;
    }
}

// ---------------- GEMM: WhT[n][m] = f16( sum_k A[m,k]*B[n,k] + bias[n] ) ----------------
// A: (4096 x K) fp32, B: (256 x K) fp32. 64x64 tile, 4 waves, f16 MFMA.
__global__ __launch_bounds__(256) void gemm16(const float* __restrict__ A,
                                              const float* __restrict__ B,
                                              const float* __restrict__ bias,
                                              u16* __restrict__ WhT, int K) {
    __shared__ u16 Al[64][40];
    __shared__ u16 Bl[64][40];
    const int tid = threadIdx.x;
    const int lane = tid & 63, wv = tid >> 6;
    const int l15 = lane & 15, g = lane >> 4;
    const int m0 = blockIdx.x * 64, n0 = blockIdx.y * 64;
    const int r = tid >> 2, c8 = (tid & 3) * 8;

    f32x4 acc[4] = {};
    for (int k0 = 0; k0 < K; k0 += 32) {
        const float4 a0 = *(const float4*)&A[(size_t)(m0 + r) * K + k0 + c8];
        const float4 a1 = *(const float4*)&A[(size_t)(m0 + r) * K + k0 + c8 + 4];
        const float4 b0 = *(const float4*)&B[(size_t)(n0 + r) * K + k0 + c8];
        const float4 b1 = *(const float4*)&B[(size_t)(n0 + r) * K + k0 + c8 + 4];
        u16x8 av, bv;
        av[0] = f16b(a0.x); av[1] = f16b(a0.y); av[2] = f16b(a0.z); av[3] = f16b(a0.w);
        av[4] = f16b(a1.x); av[5] = f16b(a1.y); av[6] = f16b(a1.z); av[7] = f16b(a1.w);
        bv[0] = f16b(b0.x); bv[1] = f16b(b0.y); bv[2] = f16b(b0.z); bv[3] = f16b(b0.w);
        bv[4] = f16b(b1.x); bv[5] = f16b(b1.y); bv[6] = f16b(b1.z); bv[7] = f16b(b1.w);
        __syncthreads();
        *(u16x8*)&Al[r][c8] = av;
        *(u16x8*)&Bl[r][c8] = bv;
        __syncthreads();
        f16x8 afr = *(const f16x8*)&Al[16 * wv + l15][8 * g];
#pragma unroll
        for (int ni = 0; ni < 4; ++ni) {
            f16x8 bfr = *(const f16x8*)&Bl[16 * ni + l15][8 * g];
            acc[ni] = __builtin_amdgcn_mfma_f32_16x16x32_f16(afr, bfr, acc[ni], 0, 0, 0);
        }
    }
#pragma unroll
    for (int ni = 0; ni < 4; ++ni) {
        const int n = n0 + 16 * ni + l15;
        const float bvs = bias[n];
        u16x4 pv;
#pragma unroll
        for (int rr = 0; rr < 4; ++rr) pv[rr] = f16b(acc[ni][rr] + bvs);
        *(u16x4*)&WhT[(size_t)n * MROWS + m0 + 16 * wv + 4 * g] = pv;
    }
}

// ---------------- exact fp32 scores: srcT[h][i] = X[i]·va[h][0] + vc, dstT likewise ----------------
__global__ __launch_bounds__(256) void srcdst_kernel(const float* __restrict__ X, int K,
                                                     const float* __restrict__ va,
                                                     const float* __restrict__ vc,
                                                     float* __restrict__ srcT,
                                                     float* __restrict__ dstT) {
    const int i = blockIdx.x * 256 + threadIdx.x;
    float acc[8] = {};
    for (int k = 0; k < K; k += 4) {
        const float4 xv = *(const float4*)&X[(size_t)i * K + k];
#pragma unroll
        for (int hs = 0; hs < 8; ++hs) {
            const float4 vv = *(const float4*)&va[(size_t)hs * K + k];
            acc[hs] += xv.x * vv.x + xv.y * vv.y + xv.z * vv.z + xv.w * vv.w;
        }
    }
#pragma unroll
    for (int h = 0; h < NHEADS; ++h) {
        srcT[h * MROWS + i] = acc[h * 2 + 0] + vc[h * 2 + 0];
        dstT[h * MROWS + i] = acc[h * 2 + 1] + vc[h * 2 + 1];
    }
}

// ---------------- per-head max of dstT ----------------
__global__ __launch_bounds__(256) void dmax_kernel(const float* __restrict__ dstT,
                                                   float* __restrict__ dm) {
    __shared__ float red[256];
    const int h = blockIdx.x;
    float m = -3.4e38f;
    for (int i = threadIdx.x; i < MROWS; i += 256) m = fmaxf(m, dstT[h * MROWS + i]);
    red[threadIdx.x] = m;
    __syncthreads();
    for (int s = 128; s > 0; s >>= 1) {
        if (threadIdx.x < s) red[threadIdx.x] = fmaxf(red[threadIdx.x], red[threadIdx.x + s]);
        __syncthreads();
    }
    if (threadIdx.x == 0) dm[h] = red[0];
}

// ---------------- attention (f16 MFMA) ----------------
// grid (128, nchunk), 256 thr (4 waves = 4 heads), 32 i-rows per block.
// w' = mask ? exp(lrelu(s_i+d_j) - C_i) : 0, C_i = lrelu(s_i + dmax_h) -> w' in (0,1].
// chunked: fp32 partial [chunk][i][260]. direct (nchunk==1): normalize, write fp32 out.
__global__ __launch_bounds__(256) void attn_kernel(const u16* __restrict__ WhT,
                                                   const float* __restrict__ srcT,
                                                   const float* __restrict__ dstT,
                                                   const u32* __restrict__ Abits,
                                                   const float* __restrict__ dm,
                                                   float* __restrict__ partial,
                                                   int jt_per_chunk,
                                                   float* __restrict__ outF) {
    const int lane = threadIdx.x & 63;
    const int h = threadIdx.x >> 6;
    const int l15 = lane & 15, g = lane >> 4;
    const int i0 = blockIdx.x * 32;
    const int chunk = blockIdx.y;

    const float dmh = dm[h];
    const float s0 = srcT[h * MROWS + i0 + l15];
    const float s1 = srcT[h * MROWS + i0 + 16 + l15];
    const float sd0 = s0 + dmh, sd1 = s1 + dmh;
    const float C0 = fmaxf(sd0, 0.01f * sd0);
    const float C1 = fmaxf(sd1, 0.01f * sd1);
    f32x4 acc[2][4] = {};
    float rowsum0 = 0.f, rowsum1 = 0.f;

    const int jt0 = chunk * jt_per_chunk;
    for (int jt = 0; jt < jt_per_chunk; ++jt) {
        const int j0 = (jt0 + jt) * 64;
        f16x8 af[2][2];
#pragma unroll
        for (int kj = 0; kj < 2; ++kj) {
            const int jk = j0 + 32 * kj + 8 * g;
            const float4 d0 = *(const float4*)&dstT[h * MROWS + jk];
            const float4 d1 = *(const float4*)&dstT[h * MROWS + jk + 4];
            float dv[8] = {d0.x, d0.y, d0.z, d0.w, d1.x, d1.y, d1.z, d1.w};
#pragma unroll
            for (int mi = 0; mi < 2; ++mi) {
                const int i = i0 + 16 * mi + l15;
                const u32 word = Abits[(size_t)i * 128 + (j0 >> 5) + kj];
                const u32 bits = (word >> (8 * g)) & 0xffu;
                const float s = mi ? s1 : s0;
                const float C = mi ? C1 : C0;
                f16x8 a;
                float rs = 0.f;
#pragma unroll
                for (int e = 0; e < 8; ++e) {
                    float t = s + dv[e];
                    t = fmaxf(t, 0.01f * t);                 // leaky_relu (slope 0.01)
                    float wv = __builtin_amdgcn_exp2f((t - C) * LOG2E);
                    wv = ((bits >> e) & 1u) ? wv : 0.f;
                    f16_t wh = (f16_t)wv;                    // round first,
                    a[e] = wh;
                    rs += (float)wh;                         // so denom matches numerator
                }
                if (mi) rowsum1 += rs; else rowsum0 += rs;
                af[mi][kj] = a;
            }
        }
#pragma unroll
        for (int kj = 0; kj < 2; ++kj) {
            const int jk = j0 + 32 * kj + 8 * g;
#pragma unroll
            for (int ni = 0; ni < 4; ++ni) {
                f16x8 b = *(const f16x8*)&WhT[(size_t)(h * COUT + 16 * ni + l15) * MROWS + jk];
                acc[0][ni] = __builtin_amdgcn_mfma_f32_16x16x32_f16(af[0][kj], b, acc[0][ni], 0, 0, 0);
                acc[1][ni] = __builtin_amdgcn_mfma_f32_16x16x32_f16(af[1][kj], b, acc[1][ni], 0, 0, 0);
            }
        }
    }
    rowsum0 += __shfl_xor(rowsum0, 16); rowsum0 += __shfl_xor(rowsum0, 32);
    rowsum1 += __shfl_xor(rowsum1, 16); rowsum1 += __shfl_xor(rowsum1, 32);

    if (partial) {
        float* pc = partial + (size_t)chunk * MROWS * 260;
#pragma unroll
        for (int mi = 0; mi < 2; ++mi)
#pragma unroll
            for (int ni = 0; ni < 4; ++ni)
#pragma unroll
                for (int rr = 0; rr < 4; ++rr) {
                    int i = i0 + 16 * mi + 4 * g + rr;
                    pc[(size_t)i * 260 + h * COUT + 16 * ni + l15] = acc[mi][ni][rr];
                }
        if (lane < 16) {
            pc[(size_t)(i0 + lane) * 260 + 256 + h] = rowsum0;
            pc[(size_t)(i0 + 16 + lane) * 260 + 256 + h] = rowsum1;
        }
    } else {
#pragma unroll
        for (int mi = 0; mi < 2; ++mi) {
            const float rsv = mi ? rowsum1 : rowsum0;
#pragma unroll
            for (int rr = 0; rr < 4; ++rr) {
                const float rs = __shfl(rsv, 4 * g + rr);
                const int i = i0 + 16 * mi + 4 * g + rr;
#pragma unroll
                for (int ni = 0; ni < 4; ++ni)
                    outF[(size_t)i * OHF + h * COUT + 16 * ni + l15] = acc[mi][ni][rr] / rs;
            }
        }
    }
}

// ---------------- combine chunked partials ----------------
__global__ __launch_bounds__(256) void combine_kernel(const float* __restrict__ partial,
                                                      int nchunk,
                                                      float* __restrict__ outF) {
    const int idx = blockIdx.x * 256 + threadIdx.x;
    const int i = idx >> 8, c = idx & 255, h = c >> 6;
    float v = 0.f, rs = 0.f;
    for (int ch = 0; ch < nchunk; ++ch) {
        const float* pc = partial + (size_t)ch * MROWS * 260 + (size_t)i * 260;
        v += pc[c];
        rs += pc[256 + h];
    }
    outF[idx] = v / rs;
}

// ---------------- classifier head, fp32 VALU ----------------
__global__ __launch_bounds__(256) void cls_kernel(const float* __restrict__ xf,
                                                  const float* __restrict__ FLw,
                                                  const float* __restrict__ FLb,
                                                  float* __restrict__ out1) {
    const int id = blockIdx.x * 256 + threadIdx.x;
    if (id >= MROWS * NCLS) return;
    const int m = id / NCLS, k = id - m * NCLS;
    float acc = FLb[k];
    for (int c = 0; c < OHF; c += 4) {
        const float4 xv = *(const float4*)&xf[(size_t)m * OHF + c];
        const float4 wv = *(const float4*)&FLw[(size_t)k * OHF + c];
        acc += xv.x * wv.x + xv.y * wv.y + xv.z * wv.z + xv.w * wv.w;
    }
    out1[id] = acc;
}

extern "C" void kernel_launch(void* const* d_in, const int* in_sizes, int n_in,
                              void* d_out, int out_size, void* d_ws, size_t ws_size,
                              hipStream_t stream) {
    const float* hIn = (const float*)d_in[0];
    const int*   A   = (const int*)d_in[1];
    const float* W1w = (const float*)d_in[2];
    const float* W1b = (const float*)d_in[3];
    const float* a1  = (const float*)d_in[4];
    const float* W3w = (const float*)d_in[5];
    const float* W3b = (const float*)d_in[6];
    const float* W2w = (const float*)d_in[7];
    const float* W2b = (const float*)d_in[8];
    const float* a2  = (const float*)d_in[9];
    const float* FLw = (const float*)d_in[10];
    const float* FLb = (const float*)d_in[11];
    float* outX = (float*)d_out;                     // x: (4096 x 256) fp32
    float* outL = outX + (size_t)MROWS * OHF;        // logits: (4096 x 40) fp32

    char* p = (char*)d_ws;
    auto alloc = [&](size_t bytes) { char* q = p; p += (bytes + 255) & ~(size_t)255; return q; };
    u32*   Abits = (u32*)alloc((size_t)MROWS * 128 * 4);
    u16*   WhT1  = (u16*)alloc((size_t)OHF * MROWS * 2);
    u16*   WhT2  = (u16*)alloc((size_t)OHF * MROWS * 2);
    float* x1f   = (float*)alloc((size_t)MROWS * OHF * 4);
    float* Cwf   = (float*)alloc((size_t)256 * 256 * 4);
    float* cbf   = (float*)alloc(256 * 4);
    float* va1   = (float*)alloc((size_t)8 * 512 * 4);
    float* vc1   = (float*)alloc(8 * 4);
    float* va2   = (float*)alloc((size_t)8 * 256 * 4);
    float* vc2   = (float*)alloc(8 * 4);
    float* srcT1 = (float*)alloc((size_t)NHEADS * MROWS * 4);
    float* dstT1 = (float*)alloc((size_t)NHEADS * MROWS * 4);
    float* srcT2 = (float*)alloc((size_t)NHEADS * MROWS * 4);
    float* dstT2 = (float*)alloc((size_t)NHEADS * MROWS * 4);
    float* dm1   = (float*)alloc(NHEADS * 4);
    float* dm2   = (float*)alloc(NHEADS * 4);
    size_t fixed = (size_t)(p - (char*)d_ws);
    int nchunk = 4;
    while (nchunk > 1 && fixed + (size_t)nchunk * MROWS * 260 * 4 > ws_size) nchunk >>= 1;
    const bool chunked = (nchunk > 1);
    float* partial = (float*)p;

    dim3 blk(256);
    bits_kernel<<<dim3(2048), blk, 0, stream>>>(A, Abits);
    cw_kernel<<<dim3(256), blk, 0, stream>>>(W2w, W3w, W3b, W2b, Cwf, cbf);
    va_kernel<<<dim3(2, 8), blk, 0, stream>>>(W1w, W1b, a1, 512, va1, vc1);
    va_kernel<<<dim3(1, 8), blk, 0, stream>>>(Cwf, cbf, a2, 256, va2, vc2);

    // ---- layer 1 ----
    gemm16<<<dim3(64, 4), blk, 0, stream>>>(hIn, W1w, W1b, WhT1, 512);
    srcdst_kernel<<<dim3(16), blk, 0, stream>>>(hIn, 512, va1, vc1, srcT1, dstT1);
    dmax_kernel<<<dim3(NHEADS), blk, 0, stream>>>(dstT1, dm1);
    attn_kernel<<<dim3(MROWS / 32, nchunk), blk, 0, stream>>>(
        WhT1, srcT1, dstT1, Abits, dm1,
        chunked ? partial : nullptr, 64 / nchunk,
        chunked ? nullptr : x1f);
    if (chunked)
        combine_kernel<<<dim3(4096), blk, 0, stream>>>(partial, nchunk, x1f);

    // ---- layer 2 (W3∘W2 fused into Cwf; scores exact from x1f via va2) ----
    gemm16<<<dim3(64, 4), blk, 0, stream>>>(x1f, Cwf, cbf, WhT2, 256);
    srcdst_kernel<<<dim3(16), blk, 0, stream>>>(x1f, 256, va2, vc2, srcT2, dstT2);
    dmax_kernel<<<dim3(NHEADS), blk, 0, stream>>>(dstT2, dm2);
    attn_kernel<<<dim3(MROWS / 32, nchunk), blk, 0, stream>>>(
        WhT2, srcT2, dstT2, Abits, dm2,
        chunked ? partial : nullptr, 64 / nchunk,
        chunked ? nullptr : outX);
    if (chunked)
        combine_kernel<<<dim3(4096), blk, 0, stream>>>(partial, nchunk, outX);

    // ---- classifier head ----
    cls_kernel<<<dim3((MROWS * NCLS + 255) / 256), blk, 0, stream>>>(
        outX, FLw, FLb, outL);
}

// Round 6
// 304.575 us; speedup vs baseline: 2.4678x; 1.0555x over previous
//
#include <hip/hip_runtime.h>
#include <hip/hip_bf16.h>

typedef _Float16 f16_t;
typedef unsigned short u16;
typedef unsigned int u32;
typedef float f32x4 __attribute__((ext_vector_type(4)));
typedef f16_t f16x8 __attribute__((ext_vector_type(8)));
typedef u16 u16x8 __attribute__((ext_vector_type(8)));
typedef u16 u16x4 __attribute__((ext_vector_type(4)));

#define MROWS 4096
#define NHEADS 4
#define COUT 64
#define OHF 256   // NHEADS*COUT
#define NCLS 40
#define LOG2E 1.4426950408889634f

static __device__ __forceinline__ u16 f16b(float x) {
    return __builtin_bit_cast(u16, (f16_t)x);
}

// ---------------- A (int32 0/1) -> bitmask (4096 x 128 u32) ----------------
__global__ __launch_bounds__(256) void bits_kernel(const int* __restrict__ A,
                                                   u32* __restrict__ Abits) {
    const int lane = threadIdx.x & 63;
    const int wid  = (blockIdx.x * blockDim.x + threadIdx.x) >> 6;
    const int nw   = (gridDim.x * blockDim.x) >> 6;
    const int nseg = MROWS * (MROWS / 64);
    for (int seg = wid; seg < nseg; seg += nw) {
        const int i  = seg >> 6;
        const int j0 = (seg & 63) * 64;
        int aval = A[(size_t)i * MROWS + j0 + lane];
        unsigned long long bal = __ballot(aval != 0);
        if (lane == 0)      Abits[(size_t)i * 128 + (j0 >> 5)]     = (u32)bal;
        else if (lane == 1) Abits[(size_t)i * 128 + (j0 >> 5) + 1] = (u32)(bal >> 32);
    }
}

// ---------------- prep: Cw=W2@W3, cb=W2@W3b+W2b, va1/vc1, va2/vc2, dmu init ----------------
__global__ __launch_bounds__(256) void prep_kernel(const float* __restrict__ W1w,
                                                   const float* __restrict__ W1b,
                                                   const float* __restrict__ a1,
                                                   const float* __restrict__ W2w,
                                                   const float* __restrict__ W2b,
                                                   const float* __restrict__ W3w,
                                                   const float* __restrict__ W3b,
                                                   const float* __restrict__ a2,
                                                   float* __restrict__ Cwf,
                                                   float* __restrict__ cbf,
                                                   float* __restrict__ va1,
                                                   float* __restrict__ vc1,
                                                   float* __restrict__ va2,
                                                   float* __restrict__ vc2,
                                                   u32* __restrict__ dmu) {
    __shared__ float u[8][64];
    const int bid = blockIdx.x, tid = threadIdx.x;
    if (bid < 256) {
        // Cwf[p][q] = sum_t W2[p][t] * W3[t][q]
        float acc = 0.f;
        for (int t = 0; t < 64; ++t)
            acc += W2w[bid * 64 + t] * W3w[t * 256 + tid];
        Cwf[bid * 256 + tid] = acc;
        if (tid == 0) {
            float b = 0.f;
            for (int t = 0; t < 64; ++t) b += W2w[bid * 64 + t] * W3b[t];
            cbf[bid] = b + W2b[bid];
        }
    } else if (bid < 258) {
        const int k = (bid - 256) * 256 + tid;
#pragma unroll
        for (int hs = 0; hs < 8; ++hs) {
            const int h = hs >> 1, s = hs & 1;
            float acc = 0.f;
            for (int c = 0; c < COUT; ++c)
                acc += W1w[(size_t)(h * COUT + c) * 512 + k] * a1[h * 128 + s * COUT + c];
            va1[hs * 512 + k] = acc;
        }
        if (bid == 256 && tid == 0) {
            for (int hs = 0; hs < 8; ++hs) {
                const int h = hs >> 1, s = hs & 1;
                float b = 0.f;
                for (int c = 0; c < COUT; ++c) b += W1b[h * COUT + c] * a1[h * 128 + s * COUT + c];
                vc1[hs] = b;
            }
        }
    } else if (bid == 258) {
        // u[hs][t] = sum_c W2[(h*64+c)][t] * a2[h][s*64+c]; va2[hs][k] = sum_t u*W3[t][k]
#pragma unroll
        for (int e = tid * 2; e < tid * 2 + 2; ++e) {
            const int hs = e >> 6, t = e & 63;
            const int h = hs >> 1, s = hs & 1;
            float acc = 0.f;
            for (int c = 0; c < COUT; ++c)
                acc += W2w[(size_t)(h * COUT + c) * 64 + t] * a2[h * 128 + s * COUT + c];
            u[hs][t] = acc;
        }
        __syncthreads();
#pragma unroll
        for (int hs = 0; hs < 8; ++hs) {
            float acc = 0.f;
            for (int t = 0; t < 64; ++t) acc += u[hs][t] * W3w[t * 256 + tid];
            va2[hs * 256 + tid] = acc;
        }
        if (tid == 0) {
            for (int hs = 0; hs < 8; ++hs) {
                const int h = hs >> 1, s = hs & 1;
                float b = 0.f;
                for (int t = 0; t < 64; ++t) b += u[hs][t] * W3b[t];
                for (int c = 0; c < COUT; ++c) b += W2b[h * COUT + c] * a2[h * 128 + s * COUT + c];
                vc2[hs] = b;
            }
        }
    } else {
        if (tid < 8) dmu[tid] = 0u;   // monotone-mapped -inf
    }
}

// ---------------- GEMM: WhT[n][m] = f16( sum_k A[m,k]*B[n,k] + bias[n] ) ----------------
__global__ __launch_bounds__(256) void gemm16(const float* __restrict__ A,
                                              const float* __restrict__ B,
                                              const float* __restrict__ bias,
                                              u16* __restrict__ WhT, int K) {
    __shared__ u16 Al[64][40];
    __shared__ u16 Bl[64][40];
    const int tid = threadIdx.x;
    const int lane = tid & 63, wv = tid >> 6;
    const int l15 = lane & 15, g = lane >> 4;
    const int m0 = blockIdx.x * 64, n0 = blockIdx.y * 64;
    const int r = tid >> 2, c8 = (tid & 3) * 8;

    f32x4 acc[4] = {};
    for (int k0 = 0; k0 < K; k0 += 32) {
        const float4 a0 = *(const float4*)&A[(size_t)(m0 + r) * K + k0 + c8];
        const float4 a1 = *(const float4*)&A[(size_t)(m0 + r) * K + k0 + c8 + 4];
        const float4 b0 = *(const float4*)&B[(size_t)(n0 + r) * K + k0 + c8];
        const float4 b1 = *(const float4*)&B[(size_t)(n0 + r) * K + k0 + c8 + 4];
        u16x8 av, bv;
        av[0] = f16b(a0.x); av[1] = f16b(a0.y); av[2] = f16b(a0.z); av[3] = f16b(a0.w);
        av[4] = f16b(a1.x); av[5] = f16b(a1.y); av[6] = f16b(a1.z); av[7] = f16b(a1.w);
        bv[0] = f16b(b0.x); bv[1] = f16b(b0.y); bv[2] = f16b(b0.z); bv[3] = f16b(b0.w);
        bv[4] = f16b(b1.x); bv[5] = f16b(b1.y); bv[6] = f16b(b1.z); bv[7] = f16b(b1.w);
        __syncthreads();
        *(u16x8*)&Al[r][c8] = av;
        *(u16x8*)&Bl[r][c8] = bv;
        __syncthreads();
        f16x8 afr = *(const f16x8*)&Al[16 * wv + l15][8 * g];
#pragma unroll
        for (int ni = 0; ni < 4; ++ni) {
            f16x8 bfr = *(const f16x8*)&Bl[16 * ni + l15][8 * g];
            acc[ni] = __builtin_amdgcn_mfma_f32_16x16x32_f16(afr, bfr, acc[ni], 0, 0, 0);
        }
    }
#pragma unroll
    for (int ni = 0; ni < 4; ++ni) {
        const int n = n0 + 16 * ni + l15;
        const float bvs = bias[n];
        u16x4 pv;
#pragma unroll
        for (int rr = 0; rr < 4; ++rr) pv[rr] = f16b(acc[ni][rr] + bvs);
        *(u16x4*)&WhT[(size_t)n * MROWS + m0 + 16 * wv + 4 * g] = pv;
    }
}

// ---------------- scores: k-sliced, fused per-head dst max (atomicMax) ----------------
// grid 128 blocks x 256 thr: 32 rows x 8 k-slices.
__global__ __launch_bounds__(256) void srcdst_kernel(const float* __restrict__ X, int K,
                                                     const float* __restrict__ va,
                                                     const float* __restrict__ vc,
                                                     float* __restrict__ srcT,
                                                     float* __restrict__ dstT,
                                                     u32* __restrict__ dmu) {
    __shared__ float red[32][8][8];   // [row][ki][hs]
    __shared__ float dred[4][32];
    const int tid = threadIdx.x;
    const int ii = tid >> 3, ki = tid & 7;
    const int i = blockIdx.x * 32 + ii;
    const int KS = K >> 3;
    const int k0 = ki * KS;
    float acc[8] = {};
    for (int k = k0; k < k0 + KS; k += 4) {
        const float4 xv = *(const float4*)&X[(size_t)i * K + k];
#pragma unroll
        for (int hs = 0; hs < 8; ++hs) {
            const float4 vv = *(const float4*)&va[(size_t)hs * K + k];
            acc[hs] += xv.x * vv.x + xv.y * vv.y + xv.z * vv.z + xv.w * vv.w;
        }
    }
#pragma unroll
    for (int hs = 0; hs < 8; ++hs) red[ii][ki][hs] = acc[hs];
    __syncthreads();
    {
        const int row = tid >> 3, hs = tid & 7, h = hs >> 1;
        float sum = 0.f;
#pragma unroll
        for (int kk = 0; kk < 8; ++kk) sum += red[row][kk][hs];
        const float val = sum + vc[hs];
        const int ig = blockIdx.x * 32 + row;
        if ((hs & 1) == 0) {
            srcT[h * MROWS + ig] = val;
        } else {
            dstT[h * MROWS + ig] = val;
            dred[h][row] = val;
        }
    }
    __syncthreads();
    if (tid < 4) {
        float m = -3.4e38f;
#pragma unroll
        for (int r = 0; r < 32; ++r) m = fmaxf(m, dred[tid][r]);
        const u32 b = __builtin_bit_cast(u32, m);
        const u32 key = (b & 0x80000000u) ? ~b : (b | 0x80000000u);
        atomicMax(dmu + tid, key);
    }
}

// ---------------- attention (f16 MFMA, 8 waves: wave = (head, mi)) ----------------
// grid (128, nchunk), 512 thr. w' = mask ? exp(lrelu(s_i+d_j) - C_i) : 0 in (0,1].
__global__ __launch_bounds__(512) void attn_kernel(const u16* __restrict__ WhT,
                                                   const float* __restrict__ srcT,
                                                   const float* __restrict__ dstT,
                                                   const u32* __restrict__ Abits,
                                                   const u32* __restrict__ dmu,
                                                   float* __restrict__ partial,
                                                   int jt_per_chunk,
                                                   float* __restrict__ outF) {
    const int lane = threadIdx.x & 63;
    const int w = threadIdx.x >> 6;        // 0..7
    const int h = w & 3, mi = w >> 2;
    const int l15 = lane & 15, g = lane >> 4;
    const int i0 = blockIdx.x * 32;
    const int chunk = blockIdx.y;
    const int irow = i0 + 16 * mi + l15;

    const u32 ku = dmu[h];
    const u32 fb = (ku & 0x80000000u) ? (ku ^ 0x80000000u) : ~ku;
    const float dmh = __builtin_bit_cast(float, fb);

    const float s = srcT[h * MROWS + irow];
    const float sd = s + dmh;
    const float C = fmaxf(sd, 0.01f * sd);
    f32x4 acc[4] = {};
    float rowsum = 0.f;

    const int jt0 = chunk * jt_per_chunk;
    for (int jt = 0; jt < jt_per_chunk; ++jt) {
        const int j0 = (jt0 + jt) * 64;
        f16x8 af[2];
#pragma unroll
        for (int kj = 0; kj < 2; ++kj) {
            const int jk = j0 + 32 * kj + 8 * g;
            const float4 d0 = *(const float4*)&dstT[h * MROWS + jk];
            const float4 d1 = *(const float4*)&dstT[h * MROWS + jk + 4];
            float dv[8] = {d0.x, d0.y, d0.z, d0.w, d1.x, d1.y, d1.z, d1.w};
            const u32 word = Abits[(size_t)irow * 128 + (j0 >> 5) + kj];
            const u32 bits = (word >> (8 * g)) & 0xffu;
            f16x8 a;
            float rs = 0.f;
#pragma unroll
            for (int e = 0; e < 8; ++e) {
                float t = s + dv[e];
                t = fmaxf(t, 0.01f * t);                 // leaky_relu (slope 0.01)
                float wv = __builtin_amdgcn_exp2f((t - C) * LOG2E);
                wv = ((bits >> e) & 1u) ? wv : 0.f;
                f16_t wh = (f16_t)wv;                    // round first,
                a[e] = wh;
                rs += (float)wh;                         // so denom matches numerator
            }
            rowsum += rs;
            af[kj] = a;
        }
#pragma unroll
        for (int kj = 0; kj < 2; ++kj) {
            const int jk = j0 + 32 * kj + 8 * g;
#pragma unroll
            for (int ni = 0; ni < 4; ++ni) {
                f16x8 b = *(const f16x8*)&WhT[(size_t)(h * COUT + 16 * ni + l15) * MROWS + jk];
                acc[ni] = __builtin_amdgcn_mfma_f32_16x16x32_f16(af[kj], b, acc[ni], 0, 0, 0);
            }
        }
    }
    rowsum += __shfl_xor(rowsum, 16);
    rowsum += __shfl_xor(rowsum, 32);

    if (partial) {
        float* pc = partial + (size_t)chunk * MROWS * 260;
#pragma unroll
        for (int ni = 0; ni < 4; ++ni)
#pragma unroll
            for (int rr = 0; rr < 4; ++rr) {
                const int i = i0 + 16 * mi + 4 * g + rr;
                pc[(size_t)i * 260 + h * COUT + 16 * ni + l15] = acc[ni][rr];
            }
        if (lane < 16)
            pc[(size_t)(i0 + 16 * mi + lane) * 260 + 256 + h] = rowsum;
    } else {
#pragma unroll
        for (int rr = 0; rr < 4; ++rr) {
            const float rs = __shfl(rowsum, 4 * g + rr);
            const int i = i0 + 16 * mi + 4 * g + rr;
#pragma unroll
            for (int ni = 0; ni < 4; ++ni)
                outF[(size_t)i * OHF + h * COUT + 16 * ni + l15] = acc[ni][rr] / rs;
        }
    }
}

// ---------------- combine chunked partials ----------------
__global__ __launch_bounds__(256) void combine_kernel(const float* __restrict__ partial,
                                                      int nchunk,
                                                      float* __restrict__ outF) {
    const int idx = blockIdx.x * 256 + threadIdx.x;
    const int i = idx >> 8, c = idx & 255, h = c >> 6;
    float v = 0.f, rs = 0.f;
    for (int ch = 0; ch < nchunk; ++ch) {
        const float* pc = partial + (size_t)ch * MROWS * 260 + (size_t)i * 260;
        v += pc[c];
        rs += pc[256 + h];
    }
    outF[idx] = v / rs;
}

// ---------------- classifier head, fp32 VALU ----------------
__global__ __launch_bounds__(256) void cls_kernel(const float* __restrict__ xf,
                                                  const float* __restrict__ FLw,
                                                  const float* __restrict__ FLb,
                                                  float* __restrict__ out1) {
    const int id = blockIdx.x * 256 + threadIdx.x;
    if (id >= MROWS * NCLS) return;
    const int m = id / NCLS, k = id - m * NCLS;
    float acc = FLb[k];
    for (int c = 0; c < OHF; c += 4) {
        const float4 xv = *(const float4*)&xf[(size_t)m * OHF + c];
        const float4 wv = *(const float4*)&FLw[(size_t)k * OHF + c];
        acc += xv.x * wv.x + xv.y * wv.y + xv.z * wv.z + xv.w * wv.w;
    }
    out1[id] = acc;
}

extern "C" void kernel_launch(void* const* d_in, const int* in_sizes, int n_in,
                              void* d_out, int out_size, void* d_ws, size_t ws_size,
                              hipStream_t stream) {
    const float* hIn = (const float*)d_in[0];
    const int*   A   = (const int*)d_in[1];
    const float* W1w = (const float*)d_in[2];
    const float* W1b = (const float*)d_in[3];
    const float* a1  = (const float*)d_in[4];
    const float* W3w = (const float*)d_in[5];
    const float* W3b = (const float*)d_in[6];
    const float* W2w = (const float*)d_in[7];
    const float* W2b = (const float*)d_in[8];
    const float* a2  = (const float*)d_in[9];
    const float* FLw = (const float*)d_in[10];
    const float* FLb = (const float*)d_in[11];
    float* outX = (float*)d_out;                     // x: (4096 x 256) fp32
    float* outL = outX + (size_t)MROWS * OHF;        // logits: (4096 x 40) fp32

    char* p = (char*)d_ws;
    auto alloc = [&](size_t bytes) { char* q = p; p += (bytes + 255) & ~(size_t)255; return q; };
    u32*   Abits = (u32*)alloc((size_t)MROWS * 128 * 4);
    u16*   WhT1  = (u16*)alloc((size_t)OHF * MROWS * 2);
    u16*   WhT2  = (u16*)alloc((size_t)OHF * MROWS * 2);
    float* x1f   = (float*)alloc((size_t)MROWS * OHF * 4);
    float* Cwf   = (float*)alloc((size_t)256 * 256 * 4);
    float* cbf   = (float*)alloc(256 * 4);
    float* va1   = (float*)alloc((size_t)8 * 512 * 4);
    float* vc1   = (float*)alloc(8 * 4);
    float* va2   = (float*)alloc((size_t)8 * 256 * 4);
    float* vc2   = (float*)alloc(8 * 4);
    float* srcT1 = (float*)alloc((size_t)NHEADS * MROWS * 4);
    float* dstT1 = (float*)alloc((size_t)NHEADS * MROWS * 4);
    float* srcT2 = (float*)alloc((size_t)NHEADS * MROWS * 4);
    float* dstT2 = (float*)alloc((size_t)NHEADS * MROWS * 4);
    u32*   dmu   = (u32*)alloc(8 * 4);               // [0..3]=layer1, [4..7]=layer2
    size_t fixed = (size_t)(p - (char*)d_ws);
    int nchunk = 8;
    while (nchunk > 1 && fixed + (size_t)nchunk * MROWS * 260 * 4 > ws_size) nchunk >>= 1;
    const bool chunked = (nchunk > 1);
    float* partial = (float*)p;

    dim3 blk(256);
    bits_kernel<<<dim3(2048), blk, 0, stream>>>(A, Abits);
    prep_kernel<<<dim3(260), blk, 0, stream>>>(W1w, W1b, a1, W2w, W2b, W3w, W3b, a2,
                                               Cwf, cbf, va1, vc1, va2, vc2, dmu);

    // ---- layer 1 ----
    gemm16<<<dim3(64, 4), blk, 0, stream>>>(hIn, W1w, W1b, WhT1, 512);
    srcdst_kernel<<<dim3(128), blk, 0, stream>>>(hIn, 512, va1, vc1, srcT1, dstT1, dmu);
    attn_kernel<<<dim3(MROWS / 32, nchunk), dim3(512), 0, stream>>>(
        WhT1, srcT1, dstT1, Abits, dmu,
        chunked ? partial : nullptr, 64 / nchunk,
        chunked ? nullptr : x1f);
    if (chunked)
        combine_kernel<<<dim3(4096), blk, 0, stream>>>(partial, nchunk, x1f);

    // ---- layer 2 (W3∘W2 fused into Cwf; scores exact from x1f via va2) ----
    gemm16<<<dim3(64, 4), blk, 0, stream>>>(x1f, Cwf, cbf, WhT2, 256);
    srcdst_kernel<<<dim3(128), blk, 0, stream>>>(x1f, 256, va2, vc2, srcT2, dstT2, dmu + 4);
    attn_kernel<<<dim3(MROWS / 32, nchunk), dim3(512), 0, stream>>>(
        WhT2, srcT2, dstT2, Abits, dmu + 4,
        chunked ? partial : nullptr, 64 / nchunk,
        chunked ? nullptr : outX);
    if (chunked)
        combine_kernel<<<dim3(4096), blk, 0, stream>>>(partial, nchunk, outX);

    // ---- classifier head ----
    cls_kernel<<<dim3((MROWS * NCLS + 255) / 256), blk, 0, stream>>>(
        outX, FLw, FLb, outL);
}

// Round 7
// 223.604 us; speedup vs baseline: 3.3614x; 1.3621x over previous
//
#include <hip/hip_runtime.h>
#include <hip/hip_bf16.h>

typedef _Float16 f16_t;
typedef unsigned short u16;
typedef unsigned int u32;
typedef float f32x4 __attribute__((ext_vector_type(4)));
typedef f16_t f16x8 __attribute__((ext_vector_type(8)));
typedef u16 u16x8 __attribute__((ext_vector_type(8)));
typedef u16 u16x4 __attribute__((ext_vector_type(4)));

#define MROWS 4096
#define NHEADS 4
#define COUT 64
#define OHF 256   // NHEADS*COUT
#define NCLS 40
#define LOG2E 1.4426950408889634f

static __device__ __forceinline__ u16 f16b(float x) {
    return __builtin_bit_cast(u16, (f16_t)x);
}

// ---------------- A (int32 0/1) -> bitmask (4096 x 128 u32) ----------------
__global__ __launch_bounds__(256) void bits_kernel(const int* __restrict__ A,
                                                   u32* __restrict__ Abits) {
    const int lane = threadIdx.x & 63;
    const int wid  = (blockIdx.x * blockDim.x + threadIdx.x) >> 6;
    const int nw   = (gridDim.x * blockDim.x) >> 6;
    const int nseg = MROWS * (MROWS / 64);
    for (int seg = wid; seg < nseg; seg += nw) {
        const int i  = seg >> 6;
        const int j0 = (seg & 63) * 64;
        int aval = A[(size_t)i * MROWS + j0 + lane];
        unsigned long long bal = __ballot(aval != 0);
        if (lane == 0)      Abits[(size_t)i * 128 + (j0 >> 5)]     = (u32)bal;
        else if (lane == 1) Abits[(size_t)i * 128 + (j0 >> 5) + 1] = (u32)(bal >> 32);
    }
}

// ---------------- prep: Cw=W2@W3, cb=W2@W3b+W2b, va1/vc1, va2/vc2, dmu init ----------------
__global__ __launch_bounds__(256) void prep_kernel(const float* __restrict__ W1w,
                                                   const float* __restrict__ W1b,
                                                   const float* __restrict__ a1,
                                                   const float* __restrict__ W2w,
                                                   const float* __restrict__ W2b,
                                                   const float* __restrict__ W3w,
                                                   const float* __restrict__ W3b,
                                                   const float* __restrict__ a2,
                                                   float* __restrict__ Cwf,
                                                   float* __restrict__ cbf,
                                                   float* __restrict__ va1,
                                                   float* __restrict__ vc1,
                                                   float* __restrict__ va2,
                                                   float* __restrict__ vc2,
                                                   u32* __restrict__ dmu) {
    __shared__ float u[8][64];
    const int bid = blockIdx.x, tid = threadIdx.x;
    if (bid < 256) {
        float acc = 0.f;
        for (int t = 0; t < 64; ++t)
            acc += W2w[bid * 64 + t] * W3w[t * 256 + tid];
        Cwf[bid * 256 + tid] = acc;
        if (tid == 0) {
            float b = 0.f;
            for (int t = 0; t < 64; ++t) b += W2w[bid * 64 + t] * W3b[t];
            cbf[bid] = b + W2b[bid];
        }
    } else if (bid < 258) {
        const int k = (bid - 256) * 256 + tid;
#pragma unroll
        for (int hs = 0; hs < 8; ++hs) {
            const int h = hs >> 1, s = hs & 1;
            float acc = 0.f;
            for (int c = 0; c < COUT; ++c)
                acc += W1w[(size_t)(h * COUT + c) * 512 + k] * a1[h * 128 + s * COUT + c];
            va1[hs * 512 + k] = acc;
        }
        if (bid == 256 && tid == 0) {
            for (int hs = 0; hs < 8; ++hs) {
                const int h = hs >> 1, s = hs & 1;
                float b = 0.f;
                for (int c = 0; c < COUT; ++c) b += W1b[h * COUT + c] * a1[h * 128 + s * COUT + c];
                vc1[hs] = b;
            }
        }
    } else if (bid == 258) {
#pragma unroll
        for (int e = tid * 2; e < tid * 2 + 2; ++e) {
            const int hs = e >> 6, t = e & 63;
            const int h = hs >> 1, s = hs & 1;
            float acc = 0.f;
            for (int c = 0; c < COUT; ++c)
                acc += W2w[(size_t)(h * COUT + c) * 64 + t] * a2[h * 128 + s * COUT + c];
            u[hs][t] = acc;
        }
        __syncthreads();
#pragma unroll
        for (int hs = 0; hs < 8; ++hs) {
            float acc = 0.f;
            for (int t = 0; t < 64; ++t) acc += u[hs][t] * W3w[t * 256 + tid];
            va2[hs * 256 + tid] = acc;
        }
        if (tid == 0) {
            for (int hs = 0; hs < 8; ++hs) {
                const int h = hs >> 1, s = hs & 1;
                float b = 0.f;
                for (int t = 0; t < 64; ++t) b += u[hs][t] * W3b[t];
                for (int c = 0; c < COUT; ++c) b += W2b[h * COUT + c] * a2[h * 128 + s * COUT + c];
                vc2[hs] = b;
            }
        }
    } else {
        if (tid < 8) dmu[tid] = 0u;   // monotone-mapped -inf
    }
}

// ---------------- GEMM: WhT[n][m] = f16( sum_k A[m,k]*B[n,k] + bias[n] ) ----------------
__global__ __launch_bounds__(256) void gemm16(const float* __restrict__ A,
                                              const float* __restrict__ B,
                                              const float* __restrict__ bias,
                                              u16* __restrict__ WhT, int K) {
    __shared__ u16 Al[64][40];
    __shared__ u16 Bl[64][40];
    const int tid = threadIdx.x;
    const int lane = tid & 63, wv = tid >> 6;
    const int l15 = lane & 15, g = lane >> 4;
    const int m0 = blockIdx.x * 64, n0 = blockIdx.y * 64;
    const int r = tid >> 2, c8 = (tid & 3) * 8;

    f32x4 acc[4] = {};
    for (int k0 = 0; k0 < K; k0 += 32) {
        const float4 a0 = *(const float4*)&A[(size_t)(m0 + r) * K + k0 + c8];
        const float4 a1 = *(const float4*)&A[(size_t)(m0 + r) * K + k0 + c8 + 4];
        const float4 b0 = *(const float4*)&B[(size_t)(n0 + r) * K + k0 + c8];
        const float4 b1 = *(const float4*)&B[(size_t)(n0 + r) * K + k0 + c8 + 4];
        u16x8 av, bv;
        av[0] = f16b(a0.x); av[1] = f16b(a0.y); av[2] = f16b(a0.z); av[3] = f16b(a0.w);
        av[4] = f16b(a1.x); av[5] = f16b(a1.y); av[6] = f16b(a1.z); av[7] = f16b(a1.w);
        bv[0] = f16b(b0.x); bv[1] = f16b(b0.y); bv[2] = f16b(b0.z); bv[3] = f16b(b0.w);
        bv[4] = f16b(b1.x); bv[5] = f16b(b1.y); bv[6] = f16b(b1.z); bv[7] = f16b(b1.w);
        __syncthreads();
        *(u16x8*)&Al[r][c8] = av;
        *(u16x8*)&Bl[r][c8] = bv;
        __syncthreads();
        f16x8 afr = *(const f16x8*)&Al[16 * wv + l15][8 * g];
#pragma unroll
        for (int ni = 0; ni < 4; ++ni) {
            f16x8 bfr = *(const f16x8*)&Bl[16 * ni + l15][8 * g];
            acc[ni] = __builtin_amdgcn_mfma_f32_16x16x32_f16(afr, bfr, acc[ni], 0, 0, 0);
        }
    }
#pragma unroll
    for (int ni = 0; ni < 4; ++ni) {
        const int n = n0 + 16 * ni + l15;
        const float bvs = bias[n];
        u16x4 pv;
#pragma unroll
        for (int rr = 0; rr < 4; ++rr) pv[rr] = f16b(acc[ni][rr] + bvs);
        *(u16x4*)&WhT[(size_t)n * MROWS + m0 + 16 * wv + 4 * g] = pv;
    }
}

// ---------------- scores: k-sliced, fused per-head dst max (atomicMax) ----------------
__global__ __launch_bounds__(256) void srcdst_kernel(const float* __restrict__ X, int K,
                                                     const float* __restrict__ va,
                                                     const float* __restrict__ vc,
                                                     float* __restrict__ srcT,
                                                     float* __restrict__ dstT,
                                                     u32* __restrict__ dmu) {
    __shared__ float red[32][8][8];   // [row][ki][hs]
    __shared__ float dred[4][32];
    const int tid = threadIdx.x;
    const int ii = tid >> 3, ki = tid & 7;
    const int i = blockIdx.x * 32 + ii;
    const int KS = K >> 3;
    const int k0 = ki * KS;
    float acc[8] = {};
    for (int k = k0; k < k0 + KS; k += 4) {
        const float4 xv = *(const float4*)&X[(size_t)i * K + k];
#pragma unroll
        for (int hs = 0; hs < 8; ++hs) {
            const float4 vv = *(const float4*)&va[(size_t)hs * K + k];
            acc[hs] += xv.x * vv.x + xv.y * vv.y + xv.z * vv.z + xv.w * vv.w;
        }
    }
#pragma unroll
    for (int hs = 0; hs < 8; ++hs) red[ii][ki][hs] = acc[hs];
    __syncthreads();
    {
        const int row = tid >> 3, hs = tid & 7, h = hs >> 1;
        float sum = 0.f;
#pragma unroll
        for (int kk = 0; kk < 8; ++kk) sum += red[row][kk][hs];
        const float val = sum + vc[hs];
        const int ig = blockIdx.x * 32 + row;
        if ((hs & 1) == 0) {
            srcT[h * MROWS + ig] = val;
        } else {
            dstT[h * MROWS + ig] = val;
            dred[h][row] = val;
        }
    }
    __syncthreads();
    if (tid < 4) {
        float m = -3.4e38f;
#pragma unroll
        for (int r = 0; r < 32; ++r) m = fmaxf(m, dred[tid][r]);
        const u32 b = __builtin_bit_cast(u32, m);
        const u32 key = (b & 0x80000000u) ? ~b : (b | 0x80000000u);
        atomicMax(dmu + tid, key);
    }
}

// ---------------- attention (f16 MFMA, LDS-staged Wh tiles, XOR swizzle) ----------------
// grid (64, nchunk), 512 thr (8 waves: wave = (h, row-half)). 64 i-rows per block.
// Each j-tile (256 c x 64 j) staged coalesced into LDS once, shared by all waves.
__global__ __launch_bounds__(512) void attn_kernel(const u16* __restrict__ WhT,
                                                   const float* __restrict__ srcT,
                                                   const float* __restrict__ dstT,
                                                   const u32* __restrict__ Abits,
                                                   const u32* __restrict__ dmu,
                                                   float* __restrict__ partial,
                                                   int jt_per_chunk,
                                                   float* __restrict__ outF) {
    __shared__ __align__(16) unsigned char whL[256 * 128];   // 32 KB swizzled [c][j]
    const int tid = threadIdx.x;
    const int lane = tid & 63, w = tid >> 6;
    const int h = w & 3, half = w >> 2;
    const int l15 = lane & 15, g = lane >> 4;
    const int i0 = blockIdx.x * 64;
    const int chunk = blockIdx.y;
    const int xorm = (l15 & 7) << 4;          // read-side swizzle (c&7 == l15&7)

    const u32 ku = dmu[h];
    const u32 fb = (ku & 0x80000000u) ? (ku ^ 0x80000000u) : ~ku;
    const float dmh = __builtin_bit_cast(float, fb);

    float s_[2], C_[2], rowsum[2] = {0.f, 0.f};
    f32x4 acc[2][4] = {};
#pragma unroll
    for (int mi = 0; mi < 2; ++mi) {
        const float s = srcT[h * MROWS + i0 + 32 * half + 16 * mi + l15];
        s_[mi] = s;
        const float sd = s + dmh;
        C_[mi] = fmaxf(sd, 0.01f * sd);
    }

    const int jt0 = chunk * jt_per_chunk;
    for (int jt = 0; jt < jt_per_chunk; ++jt) {
        const int j0 = (jt0 + jt) * 64;
        // ---- stage Wh tile: 256 c x 64 j, coalesced 16B chunks, swizzled LDS ----
        __syncthreads();
#pragma unroll
        for (int q = 0; q < 4; ++q) {
            const int eid = tid + 512 * q;
            const int c = eid >> 3, jo8 = eid & 7;
            u16x8 v = *(const u16x8*)&WhT[(size_t)c * MROWS + j0 + jo8 * 8];
            *(u16x8*)(whL + c * 128 + ((jo8 * 16) ^ ((c & 7) << 4))) = v;
        }
        __syncthreads();
        // ---- scores -> f16 A-fragments ----
        f16x8 af[2][2];
#pragma unroll
        for (int kj = 0; kj < 2; ++kj) {
            const int jk = j0 + 32 * kj + 8 * g;
            const float4 d0 = *(const float4*)&dstT[h * MROWS + jk];
            const float4 d1 = *(const float4*)&dstT[h * MROWS + jk + 4];
            float dv[8] = {d0.x, d0.y, d0.z, d0.w, d1.x, d1.y, d1.z, d1.w};
#pragma unroll
            for (int mi = 0; mi < 2; ++mi) {
                const int irow = i0 + 32 * half + 16 * mi + l15;
                const u32 word = Abits[(size_t)irow * 128 + (j0 >> 5) + kj];
                const u32 bits = (word >> (8 * g)) & 0xffu;
                f16x8 a;
                float rs = 0.f;
#pragma unroll
                for (int e = 0; e < 8; ++e) {
                    float t = s_[mi] + dv[e];
                    t = fmaxf(t, 0.01f * t);                 // leaky_relu (slope 0.01)
                    float wv = __builtin_amdgcn_exp2f((t - C_[mi]) * LOG2E);
                    wv = ((bits >> e) & 1u) ? wv : 0.f;
                    f16_t wh = (f16_t)wv;                    // round first,
                    a[e] = wh;
                    rs += (float)wh;                         // so denom matches numerator
                }
                rowsum[mi] += rs;
                af[mi][kj] = a;
            }
        }
        // ---- MFMAs: B-fragments from swizzled LDS ----
#pragma unroll
        for (int kj = 0; kj < 2; ++kj) {
#pragma unroll
            for (int ni = 0; ni < 4; ++ni) {
                const int c = h * COUT + 16 * ni + l15;
                f16x8 b = *(const f16x8*)(whL + c * 128 + ((64 * kj + 16 * g) ^ xorm));
                acc[0][ni] = __builtin_amdgcn_mfma_f32_16x16x32_f16(af[0][kj], b, acc[0][ni], 0, 0, 0);
                acc[1][ni] = __builtin_amdgcn_mfma_f32_16x16x32_f16(af[1][kj], b, acc[1][ni], 0, 0, 0);
            }
        }
    }
#pragma unroll
    for (int mi = 0; mi < 2; ++mi) {
        rowsum[mi] += __shfl_xor(rowsum[mi], 16);
        rowsum[mi] += __shfl_xor(rowsum[mi], 32);
    }

    if (partial) {
        float* pc = partial + (size_t)chunk * MROWS * 260;
#pragma unroll
        for (int mi = 0; mi < 2; ++mi) {
#pragma unroll
            for (int ni = 0; ni < 4; ++ni)
#pragma unroll
                for (int rr = 0; rr < 4; ++rr) {
                    const int i = i0 + 32 * half + 16 * mi + 4 * g + rr;
                    pc[(size_t)i * 260 + h * COUT + 16 * ni + l15] = acc[mi][ni][rr];
                }
            if (lane < 16)
                pc[(size_t)(i0 + 32 * half + 16 * mi + lane) * 260 + 256 + h] = rowsum[mi];
        }
    } else {
#pragma unroll
        for (int mi = 0; mi < 2; ++mi)
#pragma unroll
            for (int rr = 0; rr < 4; ++rr) {
                const float rs = __shfl(rowsum[mi], 4 * g + rr);
                const int i = i0 + 32 * half + 16 * mi + 4 * g + rr;
#pragma unroll
                for (int ni = 0; ni < 4; ++ni)
                    outF[(size_t)i * OHF + h * COUT + 16 * ni + l15] = acc[mi][ni][rr] / rs;
            }
    }
}

// ---------------- combine chunked partials ----------------
__global__ __launch_bounds__(256) void combine_kernel(const float* __restrict__ partial,
                                                      int nchunk,
                                                      float* __restrict__ outF) {
    const int idx = blockIdx.x * 256 + threadIdx.x;
    const int i = idx >> 8, c = idx & 255, h = c >> 6;
    float v = 0.f, rs = 0.f;
    for (int ch = 0; ch < nchunk; ++ch) {
        const float* pc = partial + (size_t)ch * MROWS * 260 + (size_t)i * 260;
        v += pc[c];
        rs += pc[256 + h];
    }
    outF[idx] = v / rs;
}

// ---------------- classifier head, fp32 VALU ----------------
__global__ __launch_bounds__(256) void cls_kernel(const float* __restrict__ xf,
                                                  const float* __restrict__ FLw,
                                                  const float* __restrict__ FLb,
                                                  float* __restrict__ out1) {
    const int id = blockIdx.x * 256 + threadIdx.x;
    if (id >= MROWS * NCLS) return;
    const int m = id / NCLS, k = id - m * NCLS;
    float acc = FLb[k];
    for (int c = 0; c < OHF; c += 4) {
        const float4 xv = *(const float4*)&xf[(size_t)m * OHF + c];
        const float4 wv = *(const float4*)&FLw[(size_t)k * OHF + c];
        acc += xv.x * wv.x + xv.y * wv.y + xv.z * wv.z + xv.w * wv.w;
    }
    out1[id] = acc;
}

extern "C" void kernel_launch(void* const* d_in, const int* in_sizes, int n_in,
                              void* d_out, int out_size, void* d_ws, size_t ws_size,
                              hipStream_t stream) {
    const float* hIn = (const float*)d_in[0];
    const int*   A   = (const int*)d_in[1];
    const float* W1w = (const float*)d_in[2];
    const float* W1b = (const float*)d_in[3];
    const float* a1  = (const float*)d_in[4];
    const float* W3w = (const float*)d_in[5];
    const float* W3b = (const float*)d_in[6];
    const float* W2w = (const float*)d_in[7];
    const float* W2b = (const float*)d_in[8];
    const float* a2  = (const float*)d_in[9];
    const float* FLw = (const float*)d_in[10];
    const float* FLb = (const float*)d_in[11];
    float* outX = (float*)d_out;                     // x: (4096 x 256) fp32
    float* outL = outX + (size_t)MROWS * OHF;        // logits: (4096 x 40) fp32

    char* p = (char*)d_ws;
    auto alloc = [&](size_t bytes) { char* q = p; p += (bytes + 255) & ~(size_t)255; return q; };
    u32*   Abits = (u32*)alloc((size_t)MROWS * 128 * 4);
    u16*   WhT1  = (u16*)alloc((size_t)OHF * MROWS * 2);
    u16*   WhT2  = (u16*)alloc((size_t)OHF * MROWS * 2);
    float* x1f   = (float*)alloc((size_t)MROWS * OHF * 4);
    float* Cwf   = (float*)alloc((size_t)256 * 256 * 4);
    float* cbf   = (float*)alloc(256 * 4);
    float* va1   = (float*)alloc((size_t)8 * 512 * 4);
    float* vc1   = (float*)alloc(8 * 4);
    float* va2   = (float*)alloc((size_t)8 * 256 * 4);
    float* vc2   = (float*)alloc(8 * 4);
    float* srcT1 = (float*)alloc((size_t)NHEADS * MROWS * 4);
    float* dstT1 = (float*)alloc((size_t)NHEADS * MROWS * 4);
    float* srcT2 = (float*)alloc((size_t)NHEADS * MROWS * 4);
    float* dstT2 = (float*)alloc((size_t)NHEADS * MROWS * 4);
    u32*   dmu   = (u32*)alloc(8 * 4);               // [0..3]=layer1, [4..7]=layer2
    size_t fixed = (size_t)(p - (char*)d_ws);
    int nchunk = 8;
    while (nchunk > 1 && fixed + (size_t)nchunk * MROWS * 260 * 4 > ws_size) nchunk >>= 1;
    const bool chunked = (nchunk > 1);
    float* partial = (float*)p;

    dim3 blk(256);
    bits_kernel<<<dim3(2048), blk, 0, stream>>>(A, Abits);
    prep_kernel<<<dim3(260), blk, 0, stream>>>(W1w, W1b, a1, W2w, W2b, W3w, W3b, a2,
                                               Cwf, cbf, va1, vc1, va2, vc2, dmu);

    // ---- layer 1 ----
    gemm16<<<dim3(64, 4), blk, 0, stream>>>(hIn, W1w, W1b, WhT1, 512);
    srcdst_kernel<<<dim3(128), blk, 0, stream>>>(hIn, 512, va1, vc1, srcT1, dstT1, dmu);
    attn_kernel<<<dim3(MROWS / 64, nchunk), dim3(512), 0, stream>>>(
        WhT1, srcT1, dstT1, Abits, dmu,
        chunked ? partial : nullptr, 64 / nchunk,
        chunked ? nullptr : x1f);
    if (chunked)
        combine_kernel<<<dim3(4096), blk, 0, stream>>>(partial, nchunk, x1f);

    // ---- layer 2 (W3∘W2 fused into Cwf; scores exact from x1f via va2) ----
    gemm16<<<dim3(64, 4), blk, 0, stream>>>(x1f, Cwf, cbf, WhT2, 256);
    srcdst_kernel<<<dim3(128), blk, 0, stream>>>(x1f, 256, va2, vc2, srcT2, dstT2, dmu + 4);
    attn_kernel<<<dim3(MROWS / 64, nchunk), dim3(512), 0, stream>>>(
        WhT2, srcT2, dstT2, Abits, dmu + 4,
        chunked ? partial : nullptr, 64 / nchunk,
        chunked ? nullptr : outX);
    if (chunked)
        combine_kernel<<<dim3(4096), blk, 0, stream>>>(partial, nchunk, outX);

    // ---- classifier head ----
    cls_kernel<<<dim3((MROWS * NCLS + 255) / 256), blk, 0, stream>>>(
        outX, FLw, FLb, outL);
}